// Round 1
// baseline (32239.178 us; speedup 1.0000x reference)
//
#include <hip/hip_runtime.h>
#include <math.h>

// ConvBlockFD: two frequency-dynamic 3x3 convs with per-sample kernel attention.
// R1 strategy: correct fp32 baseline. Compute-bound (4.64e11 FLOP); direct tiled
// conv on the vector ALU. MFMA (bf16-split) is the planned next step.

#define K_NUM 4

// ---------------- GAP: mean over HxW per (b,c) plane ----------------
__global__ void fd_gap_kernel(const float* __restrict__ x, float* __restrict__ out, int HW) {
  const float4* p = (const float4*)(x + (size_t)blockIdx.x * HW);
  int n4 = HW >> 2;
  float s = 0.f;
  for (int i = threadIdx.x; i < n4; i += blockDim.x) {
    float4 v = p[i];
    s += v.x + v.y + v.z + v.w;
  }
  for (int off = 32; off > 0; off >>= 1) s += __shfl_down(s, off, 64);
  __shared__ float wsum[4];
  int lane = threadIdx.x & 63, w = threadIdx.x >> 6;
  if (lane == 0) wsum[w] = s;
  __syncthreads();
  if (threadIdx.x == 0) {
    float t = 0.f;
    int nw = blockDim.x >> 6;
    for (int i = 0; i < nw; ++i) t += wsum[i];
    out[blockIdx.x] = t / (float)HW;
  }
}

// ---------------- attention MLP + softmax (grid = B, block = 64) ----------------
__global__ void fd_attn_kernel(const float* __restrict__ gap, int C, int Hd,
                               const float* __restrict__ w1, const float* __restrict__ b1,
                               const float* __restrict__ w2, const float* __restrict__ b2,
                               float* __restrict__ attn) {
  int b = blockIdx.x, j = threadIdx.x;
  __shared__ float h[64];
  __shared__ float z[K_NUM];
  if (j < Hd) {
    float s = b1[j];
    const float* g = gap + (size_t)b * C;
    for (int c = 0; c < C; ++c) s = fmaf(g[c], w1[c * Hd + j], s);
    h[j] = fmaxf(s, 0.f);
  }
  __syncthreads();
  if (j < K_NUM) {
    float s = b2[j];
    for (int c = 0; c < Hd; ++c) s = fmaf(h[c], w2[c * K_NUM + j], s);
    z[j] = s;
  }
  __syncthreads();
  if (j == 0) {
    float m = z[0];
    for (int k = 1; k < K_NUM; ++k) m = fmaxf(m, z[k]);
    float e[K_NUM], sum = 0.f;
    for (int k = 0; k < K_NUM; ++k) { e[k] = expf(z[k] - m); sum += e[k]; }
    for (int k = 0; k < K_NUM; ++k) attn[b * K_NUM + k] = e[k] / sum;
  }
}

// ---------------- kernel synthesis: wd[b][ci][co][9] = sum_k attn[b,k]*irfft2(F_k) ----
// irfft2 with s=(3,3) from rfft bins [3,2]:
//   G[a,v] = (1/3) sum_u F[u,v] e^{+2pi i u a/3}          (complex ifft, axis -2)
//   w[a,b] = (1/3) (Re G[a,0] + 2(Re G[a,1] cos(2pi b/3) - Im G[a,1] sin(2pi b/3)))
// (irfft drops the imaginary part of the v=0 bin.)
__global__ void fd_synth_kernel(const float* __restrict__ wfr, const float* __restrict__ wfi,
                                const float* __restrict__ attn, float* __restrict__ wd,
                                int B, int CO, int CI) {
  size_t gid = (size_t)blockIdx.x * blockDim.x + threadIdx.x;
  size_t total = (size_t)B * CI * CO;
  if (gid >= total) return;
  int co = (int)(gid % CO);
  size_t t = gid / CO;
  int ci = (int)(t % CI);
  int b = (int)(t / CI);

  float a[K_NUM];
  for (int k = 0; k < K_NUM; ++k) a[k] = attn[b * K_NUM + k];

  float Fr[3][2], Fi[3][2];
  for (int u = 0; u < 3; ++u) for (int v = 0; v < 2; ++v) { Fr[u][v] = 0.f; Fi[u][v] = 0.f; }
  for (int k = 0; k < K_NUM; ++k) {
    size_t base = ((((size_t)k * CO + co) * CI + ci) * 3) * 2;
    const float* pr = wfr + base;
    const float* pi = wfi + base;
    float ak = a[k];
    for (int u = 0; u < 3; ++u)
      for (int v = 0; v < 2; ++v) {
        Fr[u][v] = fmaf(ak, pr[u * 2 + v], Fr[u][v]);
        Fi[u][v] = fmaf(ak, pi[u * 2 + v], Fi[u][v]);
      }
  }

  const float CS[3] = {1.f, -0.5f, -0.5f};
  const float SN[3] = {0.f, 0.8660254037844386f, -0.8660254037844386f};
  float out[9];
  for (int ai = 0; ai < 3; ++ai) {
    float Gr[2], Gi[2];
    for (int v = 0; v < 2; ++v) {
      float gr = 0.f, gi = 0.f;
      for (int u = 0; u < 3; ++u) {
        int idx = (u * ai) % 3;
        gr += Fr[u][v] * CS[idx] - Fi[u][v] * SN[idx];
        gi += Fr[u][v] * SN[idx] + Fi[u][v] * CS[idx];
      }
      Gr[v] = gr * (1.f / 3.f);
      Gi[v] = gi * (1.f / 3.f);
    }
    for (int bi = 0; bi < 3; ++bi) {
      out[ai * 3 + bi] = (Gr[0] + 2.f * (Gr[1] * CS[bi] - Gi[1] * SN[bi])) * (1.f / 3.f);
    }
  }
  float* dst = wd + gid * 9;
  for (int j = 0; j < 9; ++j) dst[j] = out[j];
}

// ---------------- per-sample 3x3 conv, SAME, +bias, ReLU ----------------
// Tile: 32x32 px, CO_T=16 co per block; 256 thr: thread = (row 0..31, 4 consecutive cols).
// x staged in LDS (stride 35 -> <=2-way bank alias, free); w staged padded to 12 floats
// per (ci,co) so the 9-float reads are 16B aligned (b128+b128+b32).
template <int CI, int CO, int CI_C, int CO_T>
__global__ __launch_bounds__(256) void fd_conv3x3_kernel(
    const float* __restrict__ x, const float* __restrict__ wd,
    const float* __restrict__ bias, float* __restrict__ y, int H, int W) {
  constexpr int TW = 32, TH = 32;
  constexpr int XS = TW + 3;  // 35: pad to break 32-bank power-of-2 stride
  __shared__ float xs[CI_C][TH + 2][XS];
  __shared__ float ws[CI_C][CO_T][12];

  const int tilesX = W / TW;
  const int tx0 = (blockIdx.x % tilesX) * TW;
  const int ty0 = (blockIdx.x / tilesX) * TH;
  const int co0 = blockIdx.y * CO_T;
  const int b = blockIdx.z;
  const int tid = threadIdx.x;
  const int row = tid >> 3;         // 0..31
  const int colg = (tid & 7) * 4;   // 0,4,...,28

  float acc[CO_T][4];
  for (int i = 0; i < CO_T; ++i)
    for (int p = 0; p < 4; ++p) acc[i][p] = 0.f;

  const size_t xplane = (size_t)H * W;
  const float* xb = x + (size_t)b * CI * xplane;

  for (int cc = 0; cc < CI / CI_C; ++cc) {
    __syncthreads();
    // stage x chunk (with halo, zero-padded borders)
    constexpr int E = CI_C * 34 * 34;
    for (int li = tid; li < E; li += 256) {
      int ci = li / (34 * 34);
      int rem = li - ci * (34 * 34);
      int r = rem / 34;
      int c = rem - r * 34;
      int gy = ty0 + r - 1, gx = tx0 + c - 1;
      float v = 0.f;
      if (gy >= 0 && gy < H && gx >= 0 && gx < W)
        v = xb[(size_t)(cc * CI_C + ci) * xplane + (size_t)gy * W + gx];
      xs[ci][r][c] = v;
    }
    // stage w chunk: wd[b][ci][co][9]
    constexpr int EW = CI_C * CO_T * 9;
    for (int li = tid; li < EW; li += 256) {
      int ci = li / (CO_T * 9);
      int rem = li - ci * (CO_T * 9);
      int co = rem / 9;
      int j = rem - co * 9;
      ws[ci][co][j] = wd[(((size_t)b * CI + cc * CI_C + ci) * CO + co0 + co) * 9 + j];
    }
    __syncthreads();

    for (int ci = 0; ci < CI_C; ++ci) {
      float xv[3][6];
      for (int dr = 0; dr < 3; ++dr)
        for (int dc = 0; dc < 6; ++dc)
          xv[dr][dc] = xs[ci][row + dr][colg + dc];
#pragma unroll 4
      for (int co = 0; co < CO_T; ++co) {
        float wv[9];
        for (int j = 0; j < 9; ++j) wv[j] = ws[ci][co][j];
        for (int p = 0; p < 4; ++p) {
          float s = acc[co][p];
          for (int dr = 0; dr < 3; ++dr)
            for (int dc = 0; dc < 3; ++dc)
              s = fmaf(xv[dr][p + dc], wv[dr * 3 + dc], s);
          acc[co][p] = s;
        }
      }
    }
  }

  for (int co = 0; co < CO_T; ++co) {
    float bs = bias[co0 + co];
    float4 o;
    o.x = fmaxf(acc[co][0] + bs, 0.f);
    o.y = fmaxf(acc[co][1] + bs, 0.f);
    o.z = fmaxf(acc[co][2] + bs, 0.f);
    o.w = fmaxf(acc[co][3] + bs, 0.f);
    *(float4*)(y + ((size_t)b * CO + co0 + co) * xplane + (size_t)(ty0 + row) * W + tx0 + colg) = o;
  }
}

extern "C" void kernel_launch(void* const* d_in, const int* in_sizes, int n_in,
                              void* d_out, int out_size, void* d_ws, size_t ws_size,
                              hipStream_t stream) {
  const int B = 16, CIN = 128, COUT = 256, H = 128, W = 128;
  const int H1 = CIN / 4, H2 = COUT / 4;
  const int HW = H * W;

  const float* x    = (const float*)d_in[0];
  const float* w1fr = (const float*)d_in[1];
  const float* w1fi = (const float*)d_in[2];
  const float* b1   = (const float*)d_in[3];
  const float* a1w1 = (const float*)d_in[4];
  const float* a1b1 = (const float*)d_in[5];
  const float* a1w2 = (const float*)d_in[6];
  const float* a1b2 = (const float*)d_in[7];
  const float* w2fr = (const float*)d_in[8];
  const float* w2fi = (const float*)d_in[9];
  const float* b2   = (const float*)d_in[10];
  const float* a2w1 = (const float*)d_in[11];
  const float* a2b1 = (const float*)d_in[12];
  const float* a2w2 = (const float*)d_in[13];
  const float* a2b2 = (const float*)d_in[14];
  float* out = (float*)d_out;

  // workspace layout (floats): y1 | wd (reused layer1/layer2) | gap | attn  (~105 MB)
  float* ws = (float*)d_ws;
  float* y1    = ws;                        // 16*256*128*128 = 16,777,216
  float* wdbuf = y1 + (size_t)B * COUT * HW;  // up to 16*256*256*9 = 9,437,184
  float* gap   = wdbuf + (size_t)B * COUT * COUT * 9;  // up to 4096
  float* attn  = gap + (size_t)B * COUT;    // 64

  // ---- layer 1 ----
  fd_gap_kernel<<<B * CIN, 256, 0, stream>>>(x, gap, HW);
  fd_attn_kernel<<<B, 64, 0, stream>>>(gap, CIN, H1, a1w1, a1b1, a1w2, a1b2, attn);
  {
    size_t total = (size_t)B * CIN * COUT;
    fd_synth_kernel<<<(int)((total + 255) / 256), 256, 0, stream>>>(
        w1fr, w1fi, attn, wdbuf, B, COUT, CIN);
  }
  fd_conv3x3_kernel<128, 256, 4, 16><<<dim3((H / 32) * (W / 32), COUT / 16, B), 256, 0, stream>>>(
      x, wdbuf, b1, y1, H, W);

  // ---- layer 2 ----
  fd_gap_kernel<<<B * COUT, 256, 0, stream>>>(y1, gap, HW);
  fd_attn_kernel<<<B, 64, 0, stream>>>(gap, COUT, H2, a2w1, a2b1, a2w2, a2b2, attn);
  {
    size_t total = (size_t)B * COUT * COUT;
    fd_synth_kernel<<<(int)((total + 255) / 256), 256, 0, stream>>>(
        w2fr, w2fi, attn, wdbuf, B, COUT, COUT);
  }
  fd_conv3x3_kernel<256, 256, 4, 16><<<dim3((H / 32) * (W / 32), COUT / 16, B), 256, 0, stream>>>(
      y1, wdbuf, b2, out, H, W);
}

// Round 2
// 1363.605 us; speedup vs baseline: 23.6426x; 23.6426x over previous
//
#include <hip/hip_runtime.h>
#include <hip/hip_bf16.h>
#include <math.h>

// ConvBlockFD R2: MFMA implicit-GEMM conv (bf16 inputs, fp32 accum).
// Conv = 9 shift-GEMMs sharing one LDS x-tile (channels-last bf16, pad-40);
// weight fragments stream from L2 (no LDS); x frags deduped across row shifts.
// Layout: xt/y1t = [B][H*W][C] bf16; wd_t = [B][9][CI/8][CO][8] bf16.
// ws: y1t(134MB) + wd_t(19MB) + gap scratch. x-transpose parked in d_out
// (dead before conv2 overwrites d_out with the final fp32 output).

#define K_NUM 4
typedef __attribute__((ext_vector_type(8))) short short8;   // 8 bf16 = 4 VGPR
typedef __attribute__((ext_vector_type(4))) float f32x4;    // MFMA C/D frag

__device__ inline float bf2f(short s) {
  unsigned u = ((unsigned)(unsigned short)s) << 16;
  return __uint_as_float(u);
}
__device__ inline short f2bf(float f) {
  __hip_bfloat16 h = __float2bfloat16(f);
  return (short)*reinterpret_cast<unsigned short*>(&h);
}

// ---------------- GAP over fp32 NCHW (layer 1) ----------------
__global__ void fd_gap_kernel(const float* __restrict__ x, float* __restrict__ out, int HW) {
  const float4* p = (const float4*)(x + (size_t)blockIdx.x * HW);
  int n4 = HW >> 2;
  float s = 0.f;
  for (int i = threadIdx.x; i < n4; i += blockDim.x) {
    float4 v = p[i];
    s += v.x + v.y + v.z + v.w;
  }
  for (int off = 32; off > 0; off >>= 1) s += __shfl_down(s, off, 64);
  __shared__ float wsum[4];
  int lane = threadIdx.x & 63, w = threadIdx.x >> 6;
  if (lane == 0) wsum[w] = s;
  __syncthreads();
  if (threadIdx.x == 0) {
    float t = 0.f;
    int nw = blockDim.x >> 6;
    for (int i = 0; i < nw; ++i) t += wsum[i];
    out[blockIdx.x] = t / (float)HW;
  }
}

// ---------------- GAP over bf16 channels-last (layer 2) ----------------
__global__ void gap_t_part_kernel(const short* __restrict__ y, float* __restrict__ part) {
  const int HW = 16384, CO = 256;
  int b = blockIdx.y, ch = blockIdx.x, co = threadIdx.x;
  const short* p = y + ((size_t)b * HW + (size_t)ch * 1024) * CO + co;
  float s = 0.f;
  for (int i = 0; i < 1024; ++i) s += bf2f(p[(size_t)i * CO]);
  part[(b * 16 + ch) * CO + co] = s;
}
__global__ void gap_t_reduce_kernel(const float* __restrict__ part, float* __restrict__ gap) {
  int b = blockIdx.x, co = threadIdx.x;
  float s = 0.f;
  for (int c = 0; c < 16; ++c) s += part[(b * 16 + c) * 256 + co];
  gap[b * 256 + co] = s * (1.f / 16384.f);
}

// ---------------- attention MLP + softmax ----------------
__global__ void fd_attn_kernel(const float* __restrict__ gap, int C, int Hd,
                               const float* __restrict__ w1, const float* __restrict__ b1,
                               const float* __restrict__ w2, const float* __restrict__ b2,
                               float* __restrict__ attn) {
  int b = blockIdx.x, j = threadIdx.x;
  __shared__ float h[64];
  __shared__ float z[K_NUM];
  if (j < Hd) {
    float s = b1[j];
    const float* g = gap + (size_t)b * C;
    for (int c = 0; c < C; ++c) s = fmaf(g[c], w1[c * Hd + j], s);
    h[j] = fmaxf(s, 0.f);
  }
  __syncthreads();
  if (j < K_NUM) {
    float s = b2[j];
    for (int c = 0; c < Hd; ++c) s = fmaf(h[c], w2[c * K_NUM + j], s);
    z[j] = s;
  }
  __syncthreads();
  if (j == 0) {
    float m = z[0];
    for (int k = 1; k < K_NUM; ++k) m = fmaxf(m, z[k]);
    float e[K_NUM], sum = 0.f;
    for (int k = 0; k < K_NUM; ++k) { e[k] = expf(z[k] - m); sum += e[k]; }
    for (int k = 0; k < K_NUM; ++k) attn[b * K_NUM + k] = e[k] / sum;
  }
}

// ---------------- synthesis: irfft2 + attention mix -> wd_t[b][9][ci/8][co][8] bf16 ----
__global__ void fd_synth_t_kernel(const float* __restrict__ wfr, const float* __restrict__ wfi,
                                  const float* __restrict__ attn, short* __restrict__ wdt,
                                  int B, int CO, int CI) {
  size_t gid = (size_t)blockIdx.x * blockDim.x + threadIdx.x;
  size_t total = (size_t)B * CI * CO;
  if (gid >= total) return;
  int co = (int)(gid % CO);
  size_t t = gid / CO;
  int ci = (int)(t % CI);
  int b = (int)(t / CI);

  float a[K_NUM];
  for (int k = 0; k < K_NUM; ++k) a[k] = attn[b * K_NUM + k];

  float Fr[3][2], Fi[3][2];
  for (int u = 0; u < 3; ++u) for (int v = 0; v < 2; ++v) { Fr[u][v] = 0.f; Fi[u][v] = 0.f; }
  for (int k = 0; k < K_NUM; ++k) {
    size_t base = ((((size_t)k * CO + co) * CI + ci) * 3) * 2;
    const float* pr = wfr + base;
    const float* pi = wfi + base;
    float ak = a[k];
    for (int u = 0; u < 3; ++u)
      for (int v = 0; v < 2; ++v) {
        Fr[u][v] = fmaf(ak, pr[u * 2 + v], Fr[u][v]);
        Fi[u][v] = fmaf(ak, pi[u * 2 + v], Fi[u][v]);
      }
  }

  const float CS[3] = {1.f, -0.5f, -0.5f};
  const float SN[3] = {0.f, 0.8660254037844386f, -0.8660254037844386f};
  float outv[9];
  for (int ai = 0; ai < 3; ++ai) {
    float Gr[2], Gi[2];
    for (int v = 0; v < 2; ++v) {
      float gr = 0.f, gi = 0.f;
      for (int u = 0; u < 3; ++u) {
        int idx = (u * ai) % 3;
        gr += Fr[u][v] * CS[idx] - Fi[u][v] * SN[idx];
        gi += Fr[u][v] * SN[idx] + Fi[u][v] * CS[idx];
      }
      Gr[v] = gr * (1.f / 3.f);
      Gi[v] = gi * (1.f / 3.f);
    }
    for (int bi = 0; bi < 3; ++bi)
      outv[ai * 3 + bi] = (Gr[0] + 2.f * (Gr[1] * CS[bi] - Gi[1] * SN[bi])) * (1.f / 3.f);
  }
  int ci8 = ci >> 3, cil = ci & 7;
  for (int s = 0; s < 9; ++s)
    wdt[((((size_t)b * 9 + s) * (CI / 8) + ci8) * CO + co) * 8 + cil] = f2bf(outv[s]);
}

// ---------------- transpose fp32 NCHW -> bf16 channels-last ----------------
__global__ __launch_bounds__(256) void transpose_bf16_kernel(
    const float* __restrict__ in, short* __restrict__ out, int C) {
  const int HW = 16384;
  __shared__ short t[64 * 40];
  int tid = threadIdx.x;
  int px0 = blockIdx.x * 64, c0 = blockIdx.y * 32, b = blockIdx.z;
  int px = tid & 63, cb = tid >> 6;
#pragma unroll
  for (int i = 0; i < 8; ++i) {
    int c = i * 4 + cb;
    float v = in[((size_t)b * C + c0 + c) * HW + px0 + px];
    t[px * 40 + c] = f2bf(v);
  }
  __syncthreads();
  int px2 = tid >> 2, g = tid & 3;
  short8 v = *(const short8*)(t + px2 * 40 + g * 8);
  *(short8*)(out + ((size_t)b * HW + px0 + px2) * C + c0 + g * 8) = v;
}

// ---------------- MFMA conv: 9 shift-GEMMs, 16x16x32 bf16 ----------------
// Block: 64 co x 256 px (16x16 tile); wave: 64 co x 64 px (4x4 frags).
// MODE 0 (conv1): D=[px][co], writes bf16 channels-last. MODE 1 (conv2): D=[co][px], fp32 NCHW.
template <int CI, int MODE>
__global__ __launch_bounds__(256) void conv_mfma_kernel(
    const short* __restrict__ xin,   // [B][HW][CI] bf16
    const short* __restrict__ wdt,   // [B][9][CI/8][256][8] bf16
    const float* __restrict__ bias,  // [256]
    short* __restrict__ yout_t,      // MODE0 out
    float* __restrict__ yout_f) {    // MODE1 out
  const int H = 128, W = 128, HW = H * W, CO = 256;
  const int NKC = CI / 32;
  __shared__ short xs[18 * 18 * 40];  // [row18][col18][ci 32 pad 40] bf16

  const int tid = threadIdx.x;
  const int w = tid >> 6;
  const int lane = tid & 63;
  const int l15 = lane & 15, l4 = lane >> 4;
  const int tx0 = (blockIdx.x & 7) * 16, ty0 = (blockIdx.x >> 3) * 16;
  const int co0 = blockIdx.y * 64;
  const int b = blockIdx.z;

  f32x4 acc[4][4];
#pragma unroll
  for (int i = 0; i < 4; ++i)
#pragma unroll
    for (int j = 0; j < 4; ++j)
      acc[i][j] = (f32x4){0.f, 0.f, 0.f, 0.f};

  for (int kc = 0; kc < NKC; ++kc) {
    __syncthreads();
    // stage x tile: 18x18 px halo x 32 ci -> 1296 16B chunks
#pragma unroll
    for (int i = 0; i < 6; ++i) {
      int idx = i * 256 + tid;
      if (idx < 1296) {
        int pxi = idx >> 2, g = idx & 3;
        int r = pxi / 18, c = pxi - r * 18;
        int gy = ty0 + r - 1, gx = tx0 + c - 1;
        short8 v = {0, 0, 0, 0, 0, 0, 0, 0};
        if ((unsigned)gy < (unsigned)H && (unsigned)gx < (unsigned)W)
          v = *(const short8*)(xin + ((size_t)b * HW + gy * W + gx) * CI + kc * 32 + g * 8);
        *(short8*)(xs + pxi * 40 + g * 8) = v;
      }
    }
    __syncthreads();

#pragma unroll
    for (int dc = 0; dc < 3; ++dc) {
      // x frags: 6 distinct rows cover all (nf, dr) pairs
      short8 xf[6];
#pragma unroll
      for (int rr = 0; rr < 6; ++rr)
        xf[rr] = *(const short8*)(xs + ((4 * w + rr) * 18 + l15 + dc) * 40 + l4 * 8);
      // w frags for all 3 dr of this dc (from L2, lane-contiguous 16B)
      short8 wf[3][4];
#pragma unroll
      for (int dr = 0; dr < 3; ++dr) {
        const short* wp = wdt + ((((size_t)b * 9 + dr * 3 + dc) * (CI / 8) + kc * 4 + l4) * CO + co0 + l15) * 8;
#pragma unroll
        for (int cf = 0; cf < 4; ++cf)
          wf[dr][cf] = *(const short8*)(wp + cf * 128);
      }
#pragma unroll
      for (int dr = 0; dr < 3; ++dr)
#pragma unroll
        for (int nf = 0; nf < 4; ++nf)
#pragma unroll
          for (int cf = 0; cf < 4; ++cf) {
            if (MODE == 0)
              acc[nf][cf] = __builtin_amdgcn_mfma_f32_16x16x32_bf16(
                  xf[nf + dr], wf[dr][cf], acc[nf][cf], 0, 0, 0);
            else
              acc[nf][cf] = __builtin_amdgcn_mfma_f32_16x16x32_bf16(
                  wf[dr][cf], xf[nf + dr], acc[nf][cf], 0, 0, 0);
          }
    }
  }

  if (MODE == 0) {
    // D[m=px-col][n=co]: lane holds col = l4*4+r, co = l15; store bf16 channels-last
#pragma unroll
    for (int cf = 0; cf < 4; ++cf) {
      float bs = bias[co0 + cf * 16 + l15];
#pragma unroll
      for (int nf = 0; nf < 4; ++nf) {
        int row = ty0 + 4 * w + nf;
#pragma unroll
        for (int r = 0; r < 4; ++r) {
          int col = tx0 + l4 * 4 + r;
          float v = fmaxf(acc[nf][cf][r] + bs, 0.f);
          yout_t[((size_t)b * HW + (size_t)row * W + col) * CO + co0 + cf * 16 + l15] = f2bf(v);
        }
      }
    }
  } else {
    // D[m=co][n=px-col]: lane holds co = l4*4+r, col = l15; store fp32 NCHW
#pragma unroll
    for (int cf = 0; cf < 4; ++cf) {
#pragma unroll
      for (int r = 0; r < 4; ++r) {
        int co = co0 + cf * 16 + l4 * 4 + r;
        float bs = bias[co];
#pragma unroll
        for (int nf = 0; nf < 4; ++nf) {
          int row = ty0 + 4 * w + nf;
          int col = tx0 + l15;
          yout_f[((size_t)b * CO + co) * HW + (size_t)row * W + col] =
              fmaxf(acc[nf][cf][r] + bs, 0.f);
        }
      }
    }
  }
}

extern "C" void kernel_launch(void* const* d_in, const int* in_sizes, int n_in,
                              void* d_out, int out_size, void* d_ws, size_t ws_size,
                              hipStream_t stream) {
  const int B = 16, CIN = 128, COUT = 256, H = 128, W = 128, HW = H * W;

  const float* x    = (const float*)d_in[0];
  const float* w1fr = (const float*)d_in[1];
  const float* w1fi = (const float*)d_in[2];
  const float* b1   = (const float*)d_in[3];
  const float* a1w1 = (const float*)d_in[4];
  const float* a1b1 = (const float*)d_in[5];
  const float* a1w2 = (const float*)d_in[6];
  const float* a1b2 = (const float*)d_in[7];
  const float* w2fr = (const float*)d_in[8];
  const float* w2fi = (const float*)d_in[9];
  const float* b2   = (const float*)d_in[10];
  const float* a2w1 = (const float*)d_in[11];
  const float* a2b1 = (const float*)d_in[12];
  const float* a2w2 = (const float*)d_in[13];
  const float* a2b2 = (const float*)d_in[14];
  float* outf = (float*)d_out;

  // xt (67MB bf16) parked in d_out: read only by conv1; conv2 overwrites d_out last.
  short* xt = (short*)d_out;

  char* wsb = (char*)d_ws;
  short* y1t  = (short*)wsb;                                   // 134,217,728 B
  short* wdt  = (short*)(wsb + 134217728);                     //  18,874,368 B
  float* gprt = (float*)(wsb + 134217728 + 18874368);          //     262,144 B
  float* gap  = (float*)(wsb + 134217728 + 18874368 + 262144); //      16,384 B
  float* attn = (float*)(wsb + 134217728 + 18874368 + 262144 + 16384); // 256 B

  // ---- layer 1 ----
  transpose_bf16_kernel<<<dim3(HW / 64, CIN / 32, B), 256, 0, stream>>>(x, xt, CIN);
  fd_gap_kernel<<<B * CIN, 256, 0, stream>>>(x, gap, HW);
  fd_attn_kernel<<<B, 64, 0, stream>>>(gap, CIN, CIN / 4, a1w1, a1b1, a1w2, a1b2, attn);
  fd_synth_t_kernel<<<(B * CIN * COUT) / 256, 256, 0, stream>>>(w1fr, w1fi, attn, wdt, B, COUT, CIN);
  conv_mfma_kernel<128, 0><<<dim3(64, 4, 16), 256, 0, stream>>>(xt, wdt, b1, y1t, nullptr);

  // ---- layer 2 ----
  gap_t_part_kernel<<<dim3(16, B), 256, 0, stream>>>(y1t, gprt);
  gap_t_reduce_kernel<<<B, 256, 0, stream>>>(gprt, gap);
  fd_attn_kernel<<<B, 64, 0, stream>>>(gap, COUT, COUT / 4, a2w1, a2b1, a2w2, a2b2, attn);
  fd_synth_t_kernel<<<(B * COUT * COUT) / 256, 256, 0, stream>>>(w2fr, w2fi, attn, wdt, B, COUT, COUT);
  conv_mfma_kernel<256, 1><<<dim3(64, 4, 16), 256, 0, stream>>>(y1t, wdt, b2, nullptr, outf);
}